// Round 12
// baseline (407.344 us; speedup 1.0000x reference)
//
#include <hip/hip_runtime.h>
#include <hip/hip_bf16.h>
#include <hip/hip_fp16.h>

// GCN 3-layer forward for MI355X (gfx950).
//   1. packw_all: W1/W2/W3 -> fragment-linear hi/lo bf16 (one kernel)
//   2. rank: r = atomicAdd(cnt[dst]), eRank[e] = r (coalesced store;
//      1 edge/thread, no LDS, max TLP for the atomic chain)
//   3. 3-kernel multi-block exclusive scan -> CSR rowptr (+fused dinv)
//   4. place: pos = rowptr[dst] + eRank[e]; eSW[pos] = (src, w). No atomic.
//   5. per layer: split-bf16 MFMA GEMM (fp16 out), then wave-per-node
//      agg gather-reduce, x8 unroll, nt-hints on streams.
// R4: split-bf16 MFMA GEMM (3 MFMAs, ~2^-17 rel err). R5: H fp16.
// R6: packed int2 (src,w). R8: rank/place atomic-free placement.
// R9 lesson: feature-slicing agg multiplies per-edge instruction cost x8.
// R11 lesson: grid-split fusion shares static LDS/VGPR across roles --
//     rank blocks inherited gemm's 64KB LDS -> 20% occ, 93us. UNFUSED.
// R12: revert fusion; keep packw_all, nt stream hints, fp16 A chain.

constexpr int N_NODES = 100000;
constexpr int E_EDGES = 1600000;
constexpr int SCAN_B = (N_NODES + 1023) / 1024;  // 98 blocks of 1024 elems

typedef short short8 __attribute__((ext_vector_type(8)));
typedef float f32x4 __attribute__((ext_vector_type(4)));
typedef int iv4 __attribute__((ext_vector_type(4)));
typedef float fv2 __attribute__((ext_vector_type(2)));

// Rank: one atomic per edge, rank stored coalesced. No LDS -> high occ.
__global__ __launch_bounds__(256) void rank_kernel(
    const int* __restrict__ dst, int* __restrict__ cnt,
    int* __restrict__ eRank) {
  int e = blockIdx.x * 256 + threadIdx.x;
  if (e < E_EDGES) eRank[e] = atomicAdd(&cnt[dst[e]], 1);
}

// --- 3-kernel scan: cnt[N] -> rowptr[N+1] (exclusive), dinv fused ---
__global__ __launch_bounds__(256) void scan_part_kernel(
    const int* __restrict__ cnt, int* __restrict__ bsum) {
  __shared__ int red[256];
  const int t = threadIdx.x;
  int base = blockIdx.x * 1024 + t * 4;
  int4 v = make_int4(0, 0, 0, 0);
  if (base < N_NODES) v = *(const int4*)(cnt + base);
  red[t] = v.x + v.y + v.z + v.w;
  __syncthreads();
  for (int off = 128; off > 0; off >>= 1) {
    if (t < off) red[t] += red[t + off];
    __syncthreads();
  }
  if (t == 0) bsum[blockIdx.x] = red[0];
}

__global__ __launch_bounds__(128) void scan_tops_kernel(
    const int* __restrict__ bsum, int* __restrict__ boff,
    int* __restrict__ rowptr) {
  __shared__ int part[128];
  const int t = threadIdx.x;
  int v = (t < SCAN_B) ? bsum[t] : 0;
  part[t] = v;
  __syncthreads();
  for (int off = 1; off < 128; off <<= 1) {
    int add = (t >= off) ? part[t - off] : 0;
    __syncthreads();
    part[t] += add;
    __syncthreads();
  }
  if (t < SCAN_B) boff[t] = part[t] - v;  // exclusive
  if (t == 127) rowptr[N_NODES] = part[127];
}

__global__ __launch_bounds__(256) void scan_write_kernel(
    const int* __restrict__ cnt, const int* __restrict__ boff,
    int* __restrict__ rowptr, float* __restrict__ dinv) {
  __shared__ int part[256];
  const int t = threadIdx.x;
  int base = blockIdx.x * 1024 + t * 4;
  int4 v = make_int4(0, 0, 0, 0);
  if (base < N_NODES) v = *(const int4*)(cnt + base);
  int s = v.x + v.y + v.z + v.w;
  part[t] = s;
  __syncthreads();
  for (int off = 1; off < 256; off <<= 1) {
    int add = (t >= off) ? part[t - off] : 0;
    __syncthreads();
    part[t] += add;
    __syncthreads();
  }
  if (base < N_NODES) {
    int run = boff[blockIdx.x] + part[t] - s;
    int4 o;
    o.x = run;
    o.y = run + v.x;
    o.z = run + v.x + v.y;
    o.w = run + v.x + v.y + v.z;
    *(int4*)(rowptr + base) = o;
    float4 dv;
    dv.x = rsqrtf((float)v.x + 1.0f);  // +1 self loop
    dv.y = rsqrtf((float)v.y + 1.0f);
    dv.z = rsqrtf((float)v.z + 1.0f);
    dv.w = rsqrtf((float)v.w + 1.0f);
    *(float4*)(dinv + base) = dv;
  }
}

// Atomic-free placement; fully pipelined store.
__global__ __launch_bounds__(256) void place_kernel(
    const int* __restrict__ src, const int* __restrict__ dst,
    const int* __restrict__ eRank, const int* __restrict__ rowptr,
    const float* __restrict__ dinv, int2* __restrict__ eSW) {
  int e = blockIdx.x * 256 + threadIdx.x;
  if (e < E_EDGES) {
    int d = dst[e];
    int s = src[e];
    int pos = rowptr[d] + eRank[e];
    eSW[pos] = make_int2(s, __float_as_int(dinv[s] * dinv[d]));
  }
}

// bf16 split helpers (manual RNE; inputs finite)
__device__ inline ushort bf_round(float x) {
  uint u = __float_as_uint(x);
  return (ushort)((u + 0x7FFFu + ((u >> 16) & 1u)) >> 16);
}
__device__ inline ushort bf_split(float x, float* rem) {
  ushort h = bf_round(x);
  *rem = x - __uint_as_float((uint)h << 16);
  return h;
}

// Pack W [128][OC] f32 into fragment-linear hi/lo bf16 (runtime OC).
__device__ inline void packw_body(int id, int OC, const float* __restrict__ W,
                                  ushort* __restrict__ hi,
                                  ushort* __restrict__ lo) {
  if (id >= OC * 16) return;
  int col = id & 15;
  int g = (id >> 4) & 3;
  int ks = (id >> 6) & 3;
  int nt = id >> 8;
  int k0 = ks * 32 + g * 8;
  int n = nt * 16 + col;
  ushort h8[8], l8[8];
#pragma unroll
  for (int j = 0; j < 8; ++j) {
    float rem;
    h8[j] = bf_split(W[(size_t)(k0 + j) * OC + n], &rem);
    l8[j] = bf_round(rem);
  }
  size_t base = (size_t)id * 8;
#pragma unroll
  for (int j = 0; j < 8; ++j) {
    hi[base + j] = h8[j];
    lo[base + j] = l8[j];
  }
}

// All three weight packs in one launch (20 blocks).
__global__ __launch_bounds__(256) void packw_all_kernel(
    const float* __restrict__ W1, ushort* __restrict__ h1,
    ushort* __restrict__ l1, const float* __restrict__ W2,
    ushort* __restrict__ h2, ushort* __restrict__ l2,
    const float* __restrict__ W3, ushort* __restrict__ h3,
    ushort* __restrict__ l3) {
  int b = blockIdx.x;
  if (b < 8) packw_body(b * 256 + threadIdx.x, 128, W1, h1, l1);
  else if (b < 16) packw_body((b - 8) * 256 + threadIdx.x, 128, W2, h2, l2);
  else packw_body((b - 16) * 256 + threadIdx.x, 64, W3, h3, l3);
}

// Split-bf16 MFMA GEMM: H[N,OC] = X[N,128] @ W[128,OC], H fp16.
// 4 waves/block, 16 rows/wave (M-tile 64). W hi/lo staged in LDS.
// HALF_IN: X fp16 row-major (fp16 -> bf16 hi/lo split is exact).
template <int OC, bool HALF_IN>
__global__ __launch_bounds__(256) void gemm_kernel(
    const void* __restrict__ Xv, const ushort* __restrict__ Whi,
    const ushort* __restrict__ Wlo, __half* __restrict__ H) {
  constexpr int NT = OC / 16;
  __shared__ ushort sWhi[OC * 128];
  __shared__ ushort sWlo[OC * 128];
  const int t = threadIdx.x;
  {  // stage packed W (contiguous, coalesced uint4 copies)
    const uint4* gh = (const uint4*)Whi;
    const uint4* gl = (const uint4*)Wlo;
    uint4* sh = (uint4*)sWhi;
    uint4* sl = (uint4*)sWlo;
    for (int i = t; i < OC * 128 / 8; i += 256) {
      sh[i] = gh[i];
      sl[i] = gl[i];
    }
  }
  const int wid = t >> 6;
  const int lane = t & 63;
  const int bid = blockIdx.x;
  const int row = bid * 64 + wid * 16 + (lane & 15);
  const bool ok = row < N_NODES;
  const int g = lane >> 4;  // k-group 0..3

  short8 ahi[4], alo[4];
#pragma unroll
  for (int ks = 0; ks < 4; ++ks) {
    float f[8];
    if (ok) {
      if constexpr (HALF_IN) {
        const __half* xr = (const __half*)Xv + (size_t)row * 128;
        uint4 u = *(const uint4*)(xr + ks * 32 + g * 8);
        float2 t0 = __half22float2(*(__half2*)&u.x);
        float2 t1 = __half22float2(*(__half2*)&u.y);
        float2 t2 = __half22float2(*(__half2*)&u.z);
        float2 t3 = __half22float2(*(__half2*)&u.w);
        f[0] = t0.x; f[1] = t0.y; f[2] = t1.x; f[3] = t1.y;
        f[4] = t2.x; f[5] = t2.y; f[6] = t3.x; f[7] = t3.y;
      } else {
        const float* xr = (const float*)Xv + (size_t)row * 128;
        float4 f0 = *(const float4*)(xr + ks * 32 + g * 8);
        float4 f1 = *(const float4*)(xr + ks * 32 + g * 8 + 4);
        f[0] = f0.x; f[1] = f0.y; f[2] = f0.z; f[3] = f0.w;
        f[4] = f1.x; f[5] = f1.y; f[6] = f1.z; f[7] = f1.w;
      }
    } else {
#pragma unroll
      for (int j = 0; j < 8; ++j) f[j] = 0.f;
    }
    union { short8 v; ushort u[8]; } h, l;
#pragma unroll
    for (int j = 0; j < 8; ++j) {
      float rem;
      h.u[j] = bf_split(f[j], &rem);
      l.u[j] = bf_round(rem);
    }
    ahi[ks] = h.v;
    alo[ks] = l.v;
  }
  __syncthreads();

#pragma unroll
  for (int nt = 0; nt < NT; ++nt) {
    f32x4 acc = {0.f, 0.f, 0.f, 0.f};
#pragma unroll
    for (int ks = 0; ks < 4; ++ks) {
      int off = (((nt * 4 + ks) * 4 + g) * 16 + (lane & 15)) * 8;
      short8 bhi = *(const short8*)&sWhi[off];
      short8 blo = *(const short8*)&sWlo[off];
      acc = __builtin_amdgcn_mfma_f32_16x16x32_bf16(alo[ks], bhi, acc, 0, 0, 0);
      acc = __builtin_amdgcn_mfma_f32_16x16x32_bf16(ahi[ks], blo, acc, 0, 0, 0);
      acc = __builtin_amdgcn_mfma_f32_16x16x32_bf16(ahi[ks], bhi, acc, 0, 0, 0);
    }
    // C: col = lane&15, row_in_tile = (lane>>4)*4 + r
#pragma unroll
    for (int r = 0; r < 4; ++r) {
      int rr = bid * 64 + wid * 16 + g * 4 + r;
      if (rr < N_NODES)
        H[(size_t)rr * OC + nt * 16 + (lane & 15)] = __float2half(acc[r]);
    }
  }
}

// Wave-per-node CSR aggregation over fp16 H table, packed (src,w) edges:
// out[n] = relu(b + dinv[n]^2*H[n] + sum_e w_e*H[src_e]).
// HALF_OUT: fp16 row-major (feeds next GEMM); else f32 (final output).
// x8 unroll; nt-loads (ext_vector iv4) on once-read edge stream,
// nt-stores on the once-written output stream.
template <int OC, bool HALF_OUT>
__global__ __launch_bounds__(256) void agg_kernel(
    const __half* __restrict__ H, const int* __restrict__ rowptr,
    const int2* __restrict__ eSW, const float* __restrict__ dinv,
    const float* __restrict__ bias, void* __restrict__ out) {
  const int wave = threadIdx.x >> 6;
  const int lane = threadIdx.x & 63;
  const int n = blockIdx.x * 4 + wave;
  if (n >= N_NODES) return;
  const float dn = dinv[n];
  const float selfw = dn * dn;
  const int beg = rowptr[n], end = rowptr[n + 1];
  const int jal = min(beg + (beg & 1), end);     // align to 16B (even idx)
  const int jend = jal + ((end - jal) & ~7);     // 8-wise main loop end
  const int jend2 = jend + ((end - jend) & ~1);  // 2-wise cleanup end
  const int* eS = (const int*)eSW;               // for iv4 nt loads

  if constexpr (OC == 128) {
    const __half2* H2 = (const __half2*)H;
    float2 hv = __half22float2(H2[(size_t)n * 64 + lane]);
    float ax = hv.x * selfw, ay = hv.y * selfw;
    for (int j = beg; j < jal; ++j) {
      int2 p = eSW[j];
      float2 v = __half22float2(H2[(size_t)p.x * 64 + lane]);
      float w = __int_as_float(p.y);
      ax = fmaf(v.x, w, ax);
      ay = fmaf(v.y, w, ay);
    }
    for (int j = jal; j < jend; j += 8) {
      iv4 p0 = __builtin_nontemporal_load((const iv4*)(eS + 2 * j));
      iv4 p1 = __builtin_nontemporal_load((const iv4*)(eS + 2 * j + 4));
      iv4 p2 = __builtin_nontemporal_load((const iv4*)(eS + 2 * j + 8));
      iv4 p3 = __builtin_nontemporal_load((const iv4*)(eS + 2 * j + 12));
      __half2 h0 = H2[(size_t)p0.x * 64 + lane];
      __half2 h1 = H2[(size_t)p0.z * 64 + lane];
      __half2 h2 = H2[(size_t)p1.x * 64 + lane];
      __half2 h3 = H2[(size_t)p1.z * 64 + lane];
      __half2 h4 = H2[(size_t)p2.x * 64 + lane];
      __half2 h5 = H2[(size_t)p2.z * 64 + lane];
      __half2 h6 = H2[(size_t)p3.x * 64 + lane];
      __half2 h7 = H2[(size_t)p3.z * 64 + lane];
      float2 v0 = __half22float2(h0);
      float2 v1 = __half22float2(h1);
      float2 v2 = __half22float2(h2);
      float2 v3 = __half22float2(h3);
      float2 v4 = __half22float2(h4);
      float2 v5 = __half22float2(h5);
      float2 v6 = __half22float2(h6);
      float2 v7 = __half22float2(h7);
      ax = fmaf(v0.x, __int_as_float(p0.y), ax);
      ay = fmaf(v0.y, __int_as_float(p0.y), ay);
      ax = fmaf(v1.x, __int_as_float(p0.w), ax);
      ay = fmaf(v1.y, __int_as_float(p0.w), ay);
      ax = fmaf(v2.x, __int_as_float(p1.y), ax);
      ay = fmaf(v2.y, __int_as_float(p1.y), ay);
      ax = fmaf(v3.x, __int_as_float(p1.w), ax);
      ay = fmaf(v3.y, __int_as_float(p1.w), ay);
      ax = fmaf(v4.x, __int_as_float(p2.y), ax);
      ay = fmaf(v4.y, __int_as_float(p2.y), ay);
      ax = fmaf(v5.x, __int_as_float(p2.w), ax);
      ay = fmaf(v5.y, __int_as_float(p2.w), ay);
      ax = fmaf(v6.x, __int_as_float(p3.y), ax);
      ay = fmaf(v6.y, __int_as_float(p3.y), ay);
      ax = fmaf(v7.x, __int_as_float(p3.w), ax);
      ay = fmaf(v7.y, __int_as_float(p3.w), ay);
    }
    for (int j = jend; j < jend2; j += 2) {
      iv4 p = __builtin_nontemporal_load((const iv4*)(eS + 2 * j));
      float2 v0 = __half22float2(H2[(size_t)p.x * 64 + lane]);
      float2 v1 = __half22float2(H2[(size_t)p.z * 64 + lane]);
      ax = fmaf(v0.x, __int_as_float(p.y), ax);
      ay = fmaf(v0.y, __int_as_float(p.y), ay);
      ax = fmaf(v1.x, __int_as_float(p.w), ax);
      ay = fmaf(v1.y, __int_as_float(p.w), ay);
    }
    for (int j = jend2; j < end; ++j) {
      int2 p = eSW[j];
      float2 v = __half22float2(H2[(size_t)p.x * 64 + lane]);
      float w = __int_as_float(p.y);
      ax = fmaf(v.x, w, ax);
      ay = fmaf(v.y, w, ay);
    }
    float2 bb = ((const float2*)bias)[lane];
    float ox = fmaxf(ax + bb.x, 0.f);
    float oy = fmaxf(ay + bb.y, 0.f);
    if constexpr (HALF_OUT) {
      __half2 hp = __floats2half2_rn(ox, oy);
      uint hb;
      __builtin_memcpy(&hb, &hp, 4);
      __builtin_nontemporal_store(hb, (uint*)out + (size_t)n * 64 + lane);
    } else {
      fv2 o = {ox, oy};
      __builtin_nontemporal_store(o, (fv2*)out + (size_t)n * 64 + lane);
    }
  } else {
    float a = __half2float(H[(size_t)n * 64 + lane]) * selfw;
    for (int j = beg; j < jal; ++j) {
      int2 p = eSW[j];
      a = fmaf(__half2float(H[(size_t)p.x * 64 + lane]),
               __int_as_float(p.y), a);
    }
    for (int j = jal; j < jend; j += 8) {
      iv4 p0 = __builtin_nontemporal_load((const iv4*)(eS + 2 * j));
      iv4 p1 = __builtin_nontemporal_load((const iv4*)(eS + 2 * j + 4));
      iv4 p2 = __builtin_nontemporal_load((const iv4*)(eS + 2 * j + 8));
      iv4 p3 = __builtin_nontemporal_load((const iv4*)(eS + 2 * j + 12));
      __half h0 = H[(size_t)p0.x * 64 + lane];
      __half h1 = H[(size_t)p0.z * 64 + lane];
      __half h2 = H[(size_t)p1.x * 64 + lane];
      __half h3 = H[(size_t)p1.z * 64 + lane];
      __half h4 = H[(size_t)p2.x * 64 + lane];
      __half h5 = H[(size_t)p2.z * 64 + lane];
      __half h6 = H[(size_t)p3.x * 64 + lane];
      __half h7 = H[(size_t)p3.z * 64 + lane];
      a = fmaf(__half2float(h0), __int_as_float(p0.y), a);
      a = fmaf(__half2float(h1), __int_as_float(p0.w), a);
      a = fmaf(__half2float(h2), __int_as_float(p1.y), a);
      a = fmaf(__half2float(h3), __int_as_float(p1.w), a);
      a = fmaf(__half2float(h4), __int_as_float(p2.y), a);
      a = fmaf(__half2float(h5), __int_as_float(p2.w), a);
      a = fmaf(__half2float(h6), __int_as_float(p3.y), a);
      a = fmaf(__half2float(h7), __int_as_float(p3.w), a);
    }
    for (int j = jend; j < jend2; j += 2) {
      iv4 p = __builtin_nontemporal_load((const iv4*)(eS + 2 * j));
      a = fmaf(__half2float(H[(size_t)p.x * 64 + lane]),
               __int_as_float(p.y), a);
      a = fmaf(__half2float(H[(size_t)p.z * 64 + lane]),
               __int_as_float(p.w), a);
    }
    for (int j = jend2; j < end; ++j) {
      int2 p = eSW[j];
      a = fmaf(__half2float(H[(size_t)p.x * 64 + lane]),
               __int_as_float(p.y), a);
    }
    float o = fmaxf(a + bias[lane], 0.f);
    __builtin_nontemporal_store(o, (float*)out + (size_t)n * 64 + lane);
  }
}

extern "C" void kernel_launch(void* const* d_in, const int* in_sizes, int n_in,
                              void* d_out, int out_size, void* d_ws,
                              size_t ws_size, hipStream_t stream) {
  const float* x = (const float*)d_in[0];
  const int* ei = (const int*)d_in[1];
  const float* W1 = (const float*)d_in[2];
  const float* b1 = (const float*)d_in[3];
  const float* W2 = (const float*)d_in[4];
  const float* b2 = (const float*)d_in[5];
  const float* W3 = (const float*)d_in[6];
  const float* b3 = (const float*)d_in[7];
  const int* src = ei;
  const int* dst = ei + E_EDGES;

  size_t off = 0;
  auto alloc = [&](size_t bytes) -> void* {
    void* p = (char*)d_ws + off;
    off += (bytes + 255) & ~(size_t)255;
    return p;
  };
  int* cnt = (int*)alloc((size_t)N_NODES * 4);
  int* rowptr = (int*)alloc((size_t)(N_NODES + 1) * 4);
  float* dinv = (float*)alloc((size_t)N_NODES * 4);
  int* bsum = (int*)alloc((size_t)SCAN_B * 4);
  int* boff = (int*)alloc((size_t)SCAN_B * 4);
  int* eRank = (int*)alloc((size_t)E_EDGES * 4);
  int2* eSW = (int2*)alloc((size_t)E_EDGES * 8);
  __half* h = (__half*)alloc((size_t)N_NODES * 128 * 2);
  __half* A = (__half*)alloc((size_t)N_NODES * 128 * 2);
  ushort* wp1h = (ushort*)alloc((size_t)128 * 128 * 2);
  ushort* wp1l = (ushort*)alloc((size_t)128 * 128 * 2);
  ushort* wp2h = (ushort*)alloc((size_t)128 * 128 * 2);
  ushort* wp2l = (ushort*)alloc((size_t)128 * 128 * 2);
  ushort* wp3h = (ushort*)alloc((size_t)128 * 64 * 2);
  ushort* wp3l = (ushort*)alloc((size_t)128 * 64 * 2);

  hipMemsetAsync(cnt, 0, (size_t)N_NODES * 4, stream);

  const int EB = (E_EDGES + 255) / 256;  // 6250
  const int GB = (N_NODES + 63) / 64;    // 1563
  const int AB = (N_NODES + 3) / 4;      // 25000

  packw_all_kernel<<<20, 256, 0, stream>>>(W1, wp1h, wp1l, W2, wp2h, wp2l, W3,
                                           wp3h, wp3l);
  rank_kernel<<<EB, 256, 0, stream>>>(dst, cnt, eRank);
  gemm_kernel<128, false><<<GB, 256, 0, stream>>>(x, wp1h, wp1l, h);
  scan_part_kernel<<<SCAN_B, 256, 0, stream>>>(cnt, bsum);
  scan_tops_kernel<<<1, 128, 0, stream>>>(bsum, boff, rowptr);
  scan_write_kernel<<<SCAN_B, 256, 0, stream>>>(cnt, boff, rowptr, dinv);
  place_kernel<<<EB, 256, 0, stream>>>(src, dst, eRank, rowptr, dinv, eSW);

  agg_kernel<128, true><<<AB, 256, 0, stream>>>(h, rowptr, eSW, dinv, b1, A);
  gemm_kernel<128, true><<<GB, 256, 0, stream>>>(A, wp2h, wp2l, h);
  agg_kernel<128, true><<<AB, 256, 0, stream>>>(h, rowptr, eSW, dinv, b2, A);
  gemm_kernel<64, true><<<GB, 256, 0, stream>>>(A, wp3h, wp3l, h);
  agg_kernel<64, false><<<AB, 256, 0, stream>>>(h, rowptr, eSW, dinv, b3,
                                                d_out);
}

// Round 13
// 370.511 us; speedup vs baseline: 1.0994x; 1.0994x over previous
//
#include <hip/hip_runtime.h>
#include <hip/hip_bf16.h>
#include <hip/hip_fp16.h>

// GCN 3-layer forward for MI355X (gfx950).
//   1. packw_all: W1/W2/W3 -> fragment-linear hi/lo bf16 (one kernel)
//   2. rank: r = atomicAdd(cnt[dst]), eRank[e] = r (coalesced store;
//      1 edge/thread, no LDS, max TLP for the atomic chain)
//   3. 3-kernel multi-block exclusive scan -> CSR rowptr (+fused dinv)
//   4. place: pos = rowptr[dst] + eRank[e]; eSW[pos] = (src, w). No atomic.
//   5. per layer: split-bf16 MFMA GEMM (fp16 out), then wave-per-node
//      agg gather-reduce, x8 unroll. fp16 A chain (exact hi/lo split).
// R4: split-bf16 MFMA GEMM (3 MFMAs, ~2^-17 rel err). R5: H fp16.
// R6: packed int2 (src,w). R8: rank/place atomic-free placement.
// R9 lesson: feature-slicing agg multiplies per-edge instruction cost x8.
// R11 lesson: grid-split fusion shares static LDS/VGPR across roles.
// R12 lesson: nontemporal hints on gfx950 DEMOTE streaming accesses
//     (agg 72.7 -> 81 us, hbm 3.45 -> 2.82 TB/s) -> REMOVED.
// R13: R12 minus nt hints; keep fp16 A chain + fused packw.

constexpr int N_NODES = 100000;
constexpr int E_EDGES = 1600000;
constexpr int SCAN_B = (N_NODES + 1023) / 1024;  // 98 blocks of 1024 elems

typedef short short8 __attribute__((ext_vector_type(8)));
typedef float f32x4 __attribute__((ext_vector_type(4)));

// Rank: one atomic per edge, rank stored coalesced. No LDS -> high occ.
__global__ __launch_bounds__(256) void rank_kernel(
    const int* __restrict__ dst, int* __restrict__ cnt,
    int* __restrict__ eRank) {
  int e = blockIdx.x * 256 + threadIdx.x;
  if (e < E_EDGES) eRank[e] = atomicAdd(&cnt[dst[e]], 1);
}

// --- 3-kernel scan: cnt[N] -> rowptr[N+1] (exclusive), dinv fused ---
__global__ __launch_bounds__(256) void scan_part_kernel(
    const int* __restrict__ cnt, int* __restrict__ bsum) {
  __shared__ int red[256];
  const int t = threadIdx.x;
  int base = blockIdx.x * 1024 + t * 4;
  int4 v = make_int4(0, 0, 0, 0);
  if (base < N_NODES) v = *(const int4*)(cnt + base);
  red[t] = v.x + v.y + v.z + v.w;
  __syncthreads();
  for (int off = 128; off > 0; off >>= 1) {
    if (t < off) red[t] += red[t + off];
    __syncthreads();
  }
  if (t == 0) bsum[blockIdx.x] = red[0];
}

__global__ __launch_bounds__(128) void scan_tops_kernel(
    const int* __restrict__ bsum, int* __restrict__ boff,
    int* __restrict__ rowptr) {
  __shared__ int part[128];
  const int t = threadIdx.x;
  int v = (t < SCAN_B) ? bsum[t] : 0;
  part[t] = v;
  __syncthreads();
  for (int off = 1; off < 128; off <<= 1) {
    int add = (t >= off) ? part[t - off] : 0;
    __syncthreads();
    part[t] += add;
    __syncthreads();
  }
  if (t < SCAN_B) boff[t] = part[t] - v;  // exclusive
  if (t == 127) rowptr[N_NODES] = part[127];
}

__global__ __launch_bounds__(256) void scan_write_kernel(
    const int* __restrict__ cnt, const int* __restrict__ boff,
    int* __restrict__ rowptr, float* __restrict__ dinv) {
  __shared__ int part[256];
  const int t = threadIdx.x;
  int base = blockIdx.x * 1024 + t * 4;
  int4 v = make_int4(0, 0, 0, 0);
  if (base < N_NODES) v = *(const int4*)(cnt + base);
  int s = v.x + v.y + v.z + v.w;
  part[t] = s;
  __syncthreads();
  for (int off = 1; off < 256; off <<= 1) {
    int add = (t >= off) ? part[t - off] : 0;
    __syncthreads();
    part[t] += add;
    __syncthreads();
  }
  if (base < N_NODES) {
    int run = boff[blockIdx.x] + part[t] - s;
    int4 o;
    o.x = run;
    o.y = run + v.x;
    o.z = run + v.x + v.y;
    o.w = run + v.x + v.y + v.z;
    *(int4*)(rowptr + base) = o;
    float4 dv;
    dv.x = rsqrtf((float)v.x + 1.0f);  // +1 self loop
    dv.y = rsqrtf((float)v.y + 1.0f);
    dv.z = rsqrtf((float)v.z + 1.0f);
    dv.w = rsqrtf((float)v.w + 1.0f);
    *(float4*)(dinv + base) = dv;
  }
}

// Atomic-free placement; fully pipelined store.
__global__ __launch_bounds__(256) void place_kernel(
    const int* __restrict__ src, const int* __restrict__ dst,
    const int* __restrict__ eRank, const int* __restrict__ rowptr,
    const float* __restrict__ dinv, int2* __restrict__ eSW) {
  int e = blockIdx.x * 256 + threadIdx.x;
  if (e < E_EDGES) {
    int d = dst[e];
    int s = src[e];
    int pos = rowptr[d] + eRank[e];
    eSW[pos] = make_int2(s, __float_as_int(dinv[s] * dinv[d]));
  }
}

// bf16 split helpers (manual RNE; inputs finite)
__device__ inline ushort bf_round(float x) {
  uint u = __float_as_uint(x);
  return (ushort)((u + 0x7FFFu + ((u >> 16) & 1u)) >> 16);
}
__device__ inline ushort bf_split(float x, float* rem) {
  ushort h = bf_round(x);
  *rem = x - __uint_as_float((uint)h << 16);
  return h;
}

// Pack W [128][OC] f32 into fragment-linear hi/lo bf16 (runtime OC).
__device__ inline void packw_body(int id, int OC, const float* __restrict__ W,
                                  ushort* __restrict__ hi,
                                  ushort* __restrict__ lo) {
  if (id >= OC * 16) return;
  int col = id & 15;
  int g = (id >> 4) & 3;
  int ks = (id >> 6) & 3;
  int nt = id >> 8;
  int k0 = ks * 32 + g * 8;
  int n = nt * 16 + col;
  ushort h8[8], l8[8];
#pragma unroll
  for (int j = 0; j < 8; ++j) {
    float rem;
    h8[j] = bf_split(W[(size_t)(k0 + j) * OC + n], &rem);
    l8[j] = bf_round(rem);
  }
  size_t base = (size_t)id * 8;
#pragma unroll
  for (int j = 0; j < 8; ++j) {
    hi[base + j] = h8[j];
    lo[base + j] = l8[j];
  }
}

// All three weight packs in one launch (20 blocks).
__global__ __launch_bounds__(256) void packw_all_kernel(
    const float* __restrict__ W1, ushort* __restrict__ h1,
    ushort* __restrict__ l1, const float* __restrict__ W2,
    ushort* __restrict__ h2, ushort* __restrict__ l2,
    const float* __restrict__ W3, ushort* __restrict__ h3,
    ushort* __restrict__ l3) {
  int b = blockIdx.x;
  if (b < 8) packw_body(b * 256 + threadIdx.x, 128, W1, h1, l1);
  else if (b < 16) packw_body((b - 8) * 256 + threadIdx.x, 128, W2, h2, l2);
  else packw_body((b - 16) * 256 + threadIdx.x, 64, W3, h3, l3);
}

// Split-bf16 MFMA GEMM: H[N,OC] = X[N,128] @ W[128,OC], H fp16.
// 4 waves/block, 16 rows/wave (M-tile 64). W hi/lo staged in LDS.
// HALF_IN: X fp16 row-major (fp16 -> bf16 hi/lo split is exact).
template <int OC, bool HALF_IN>
__global__ __launch_bounds__(256) void gemm_kernel(
    const void* __restrict__ Xv, const ushort* __restrict__ Whi,
    const ushort* __restrict__ Wlo, __half* __restrict__ H) {
  constexpr int NT = OC / 16;
  __shared__ ushort sWhi[OC * 128];
  __shared__ ushort sWlo[OC * 128];
  const int t = threadIdx.x;
  {  // stage packed W (contiguous, coalesced uint4 copies)
    const uint4* gh = (const uint4*)Whi;
    const uint4* gl = (const uint4*)Wlo;
    uint4* sh = (uint4*)sWhi;
    uint4* sl = (uint4*)sWlo;
    for (int i = t; i < OC * 128 / 8; i += 256) {
      sh[i] = gh[i];
      sl[i] = gl[i];
    }
  }
  const int wid = t >> 6;
  const int lane = t & 63;
  const int bid = blockIdx.x;
  const int row = bid * 64 + wid * 16 + (lane & 15);
  const bool ok = row < N_NODES;
  const int g = lane >> 4;  // k-group 0..3

  short8 ahi[4], alo[4];
#pragma unroll
  for (int ks = 0; ks < 4; ++ks) {
    float f[8];
    if (ok) {
      if constexpr (HALF_IN) {
        const __half* xr = (const __half*)Xv + (size_t)row * 128;
        uint4 u = *(const uint4*)(xr + ks * 32 + g * 8);
        float2 t0 = __half22float2(*(__half2*)&u.x);
        float2 t1 = __half22float2(*(__half2*)&u.y);
        float2 t2 = __half22float2(*(__half2*)&u.z);
        float2 t3 = __half22float2(*(__half2*)&u.w);
        f[0] = t0.x; f[1] = t0.y; f[2] = t1.x; f[3] = t1.y;
        f[4] = t2.x; f[5] = t2.y; f[6] = t3.x; f[7] = t3.y;
      } else {
        const float* xr = (const float*)Xv + (size_t)row * 128;
        float4 f0 = *(const float4*)(xr + ks * 32 + g * 8);
        float4 f1 = *(const float4*)(xr + ks * 32 + g * 8 + 4);
        f[0] = f0.x; f[1] = f0.y; f[2] = f0.z; f[3] = f0.w;
        f[4] = f1.x; f[5] = f1.y; f[6] = f1.z; f[7] = f1.w;
      }
    } else {
#pragma unroll
      for (int j = 0; j < 8; ++j) f[j] = 0.f;
    }
    union { short8 v; ushort u[8]; } h, l;
#pragma unroll
    for (int j = 0; j < 8; ++j) {
      float rem;
      h.u[j] = bf_split(f[j], &rem);
      l.u[j] = bf_round(rem);
    }
    ahi[ks] = h.v;
    alo[ks] = l.v;
  }
  __syncthreads();

#pragma unroll
  for (int nt = 0; nt < NT; ++nt) {
    f32x4 acc = {0.f, 0.f, 0.f, 0.f};
#pragma unroll
    for (int ks = 0; ks < 4; ++ks) {
      int off = (((nt * 4 + ks) * 4 + g) * 16 + (lane & 15)) * 8;
      short8 bhi = *(const short8*)&sWhi[off];
      short8 blo = *(const short8*)&sWlo[off];
      acc = __builtin_amdgcn_mfma_f32_16x16x32_bf16(alo[ks], bhi, acc, 0, 0, 0);
      acc = __builtin_amdgcn_mfma_f32_16x16x32_bf16(ahi[ks], blo, acc, 0, 0, 0);
      acc = __builtin_amdgcn_mfma_f32_16x16x32_bf16(ahi[ks], bhi, acc, 0, 0, 0);
    }
    // C: col = lane&15, row_in_tile = (lane>>4)*4 + r
#pragma unroll
    for (int r = 0; r < 4; ++r) {
      int rr = bid * 64 + wid * 16 + g * 4 + r;
      if (rr < N_NODES)
        H[(size_t)rr * OC + nt * 16 + (lane & 15)] = __float2half(acc[r]);
    }
  }
}

// Wave-per-node CSR aggregation over fp16 H table, packed (src,w) edges:
// out[n] = relu(b + dinv[n]^2*H[n] + sum_e w_e*H[src_e]).
// HALF_OUT: fp16 row-major (feeds next GEMM); else f32 (final output).
// Edge loop unrolled x8 (int4 loads of 2 packed edges each): eight
// independent H-row gathers in flight per wave.
template <int OC, bool HALF_OUT>
__global__ __launch_bounds__(256) void agg_kernel(
    const __half* __restrict__ H, const int* __restrict__ rowptr,
    const int2* __restrict__ eSW, const float* __restrict__ dinv,
    const float* __restrict__ bias, void* __restrict__ out) {
  const int wave = threadIdx.x >> 6;
  const int lane = threadIdx.x & 63;
  const int n = blockIdx.x * 4 + wave;
  if (n >= N_NODES) return;
  const float dn = dinv[n];
  const float selfw = dn * dn;
  const int beg = rowptr[n], end = rowptr[n + 1];
  const int jal = min(beg + (beg & 1), end);     // align to 16B (even idx)
  const int jend = jal + ((end - jal) & ~7);     // 8-wise main loop end
  const int jend2 = jend + ((end - jend) & ~1);  // 2-wise cleanup end

  if constexpr (OC == 128) {
    const __half2* H2 = (const __half2*)H;
    float2 hv = __half22float2(H2[(size_t)n * 64 + lane]);
    float ax = hv.x * selfw, ay = hv.y * selfw;
    for (int j = beg; j < jal; ++j) {
      int2 p = eSW[j];
      float2 v = __half22float2(H2[(size_t)p.x * 64 + lane]);
      float w = __int_as_float(p.y);
      ax = fmaf(v.x, w, ax);
      ay = fmaf(v.y, w, ay);
    }
    for (int j = jal; j < jend; j += 8) {
      int4 p0 = *(const int4*)(eSW + j);      // s0 w0 s1 w1
      int4 p1 = *(const int4*)(eSW + j + 2);
      int4 p2 = *(const int4*)(eSW + j + 4);
      int4 p3 = *(const int4*)(eSW + j + 6);
      __half2 h0 = H2[(size_t)p0.x * 64 + lane];
      __half2 h1 = H2[(size_t)p0.z * 64 + lane];
      __half2 h2 = H2[(size_t)p1.x * 64 + lane];
      __half2 h3 = H2[(size_t)p1.z * 64 + lane];
      __half2 h4 = H2[(size_t)p2.x * 64 + lane];
      __half2 h5 = H2[(size_t)p2.z * 64 + lane];
      __half2 h6 = H2[(size_t)p3.x * 64 + lane];
      __half2 h7 = H2[(size_t)p3.z * 64 + lane];
      float2 v0 = __half22float2(h0);
      float2 v1 = __half22float2(h1);
      float2 v2 = __half22float2(h2);
      float2 v3 = __half22float2(h3);
      float2 v4 = __half22float2(h4);
      float2 v5 = __half22float2(h5);
      float2 v6 = __half22float2(h6);
      float2 v7 = __half22float2(h7);
      ax = fmaf(v0.x, __int_as_float(p0.y), ax);
      ay = fmaf(v0.y, __int_as_float(p0.y), ay);
      ax = fmaf(v1.x, __int_as_float(p0.w), ax);
      ay = fmaf(v1.y, __int_as_float(p0.w), ay);
      ax = fmaf(v2.x, __int_as_float(p1.y), ax);
      ay = fmaf(v2.y, __int_as_float(p1.y), ay);
      ax = fmaf(v3.x, __int_as_float(p1.w), ax);
      ay = fmaf(v3.y, __int_as_float(p1.w), ay);
      ax = fmaf(v4.x, __int_as_float(p2.y), ax);
      ay = fmaf(v4.y, __int_as_float(p2.y), ay);
      ax = fmaf(v5.x, __int_as_float(p2.w), ax);
      ay = fmaf(v5.y, __int_as_float(p2.w), ay);
      ax = fmaf(v6.x, __int_as_float(p3.y), ax);
      ay = fmaf(v6.y, __int_as_float(p3.y), ay);
      ax = fmaf(v7.x, __int_as_float(p3.w), ax);
      ay = fmaf(v7.y, __int_as_float(p3.w), ay);
    }
    for (int j = jend; j < jend2; j += 2) {
      int4 p = *(const int4*)(eSW + j);
      float2 v0 = __half22float2(H2[(size_t)p.x * 64 + lane]);
      float2 v1 = __half22float2(H2[(size_t)p.z * 64 + lane]);
      ax = fmaf(v0.x, __int_as_float(p.y), ax);
      ay = fmaf(v0.y, __int_as_float(p.y), ay);
      ax = fmaf(v1.x, __int_as_float(p.w), ax);
      ay = fmaf(v1.y, __int_as_float(p.w), ay);
    }
    for (int j = jend2; j < end; ++j) {
      int2 p = eSW[j];
      float2 v = __half22float2(H2[(size_t)p.x * 64 + lane]);
      float w = __int_as_float(p.y);
      ax = fmaf(v.x, w, ax);
      ay = fmaf(v.y, w, ay);
    }
    float2 bb = ((const float2*)bias)[lane];
    float ox = fmaxf(ax + bb.x, 0.f);
    float oy = fmaxf(ay + bb.y, 0.f);
    if constexpr (HALF_OUT) {
      ((__half2*)out)[(size_t)n * 64 + lane] = __floats2half2_rn(ox, oy);
    } else {
      ((float2*)out)[(size_t)n * 64 + lane] = make_float2(ox, oy);
    }
  } else {
    float a = __half2float(H[(size_t)n * 64 + lane]) * selfw;
    for (int j = beg; j < jal; ++j) {
      int2 p = eSW[j];
      a = fmaf(__half2float(H[(size_t)p.x * 64 + lane]),
               __int_as_float(p.y), a);
    }
    for (int j = jal; j < jend; j += 8) {
      int4 p0 = *(const int4*)(eSW + j);
      int4 p1 = *(const int4*)(eSW + j + 2);
      int4 p2 = *(const int4*)(eSW + j + 4);
      int4 p3 = *(const int4*)(eSW + j + 6);
      __half h0 = H[(size_t)p0.x * 64 + lane];
      __half h1 = H[(size_t)p0.z * 64 + lane];
      __half h2 = H[(size_t)p1.x * 64 + lane];
      __half h3 = H[(size_t)p1.z * 64 + lane];
      __half h4 = H[(size_t)p2.x * 64 + lane];
      __half h5 = H[(size_t)p2.z * 64 + lane];
      __half h6 = H[(size_t)p3.x * 64 + lane];
      __half h7 = H[(size_t)p3.z * 64 + lane];
      a = fmaf(__half2float(h0), __int_as_float(p0.y), a);
      a = fmaf(__half2float(h1), __int_as_float(p0.w), a);
      a = fmaf(__half2float(h2), __int_as_float(p1.y), a);
      a = fmaf(__half2float(h3), __int_as_float(p1.w), a);
      a = fmaf(__half2float(h4), __int_as_float(p2.y), a);
      a = fmaf(__half2float(h5), __int_as_float(p2.w), a);
      a = fmaf(__half2float(h6), __int_as_float(p3.y), a);
      a = fmaf(__half2float(h7), __int_as_float(p3.w), a);
    }
    for (int j = jend; j < jend2; j += 2) {
      int4 p = *(const int4*)(eSW + j);
      a = fmaf(__half2float(H[(size_t)p.x * 64 + lane]),
               __int_as_float(p.y), a);
      a = fmaf(__half2float(H[(size_t)p.z * 64 + lane]),
               __int_as_float(p.w), a);
    }
    for (int j = jend2; j < end; ++j) {
      int2 p = eSW[j];
      a = fmaf(__half2float(H[(size_t)p.x * 64 + lane]),
               __int_as_float(p.y), a);
    }
    ((float*)out)[(size_t)n * 64 + lane] = fmaxf(a + bias[lane], 0.f);
  }
}

extern "C" void kernel_launch(void* const* d_in, const int* in_sizes, int n_in,
                              void* d_out, int out_size, void* d_ws,
                              size_t ws_size, hipStream_t stream) {
  const float* x = (const float*)d_in[0];
  const int* ei = (const int*)d_in[1];
  const float* W1 = (const float*)d_in[2];
  const float* b1 = (const float*)d_in[3];
  const float* W2 = (const float*)d_in[4];
  const float* b2 = (const float*)d_in[5];
  const float* W3 = (const float*)d_in[6];
  const float* b3 = (const float*)d_in[7];
  const int* src = ei;
  const int* dst = ei + E_EDGES;

  size_t off = 0;
  auto alloc = [&](size_t bytes) -> void* {
    void* p = (char*)d_ws + off;
    off += (bytes + 255) & ~(size_t)255;
    return p;
  };
  int* cnt = (int*)alloc((size_t)N_NODES * 4);
  int* rowptr = (int*)alloc((size_t)(N_NODES + 1) * 4);
  float* dinv = (float*)alloc((size_t)N_NODES * 4);
  int* bsum = (int*)alloc((size_t)SCAN_B * 4);
  int* boff = (int*)alloc((size_t)SCAN_B * 4);
  int* eRank = (int*)alloc((size_t)E_EDGES * 4);
  int2* eSW = (int2*)alloc((size_t)E_EDGES * 8);
  __half* h = (__half*)alloc((size_t)N_NODES * 128 * 2);
  __half* A = (__half*)alloc((size_t)N_NODES * 128 * 2);
  ushort* wp1h = (ushort*)alloc((size_t)128 * 128 * 2);
  ushort* wp1l = (ushort*)alloc((size_t)128 * 128 * 2);
  ushort* wp2h = (ushort*)alloc((size_t)128 * 128 * 2);
  ushort* wp2l = (ushort*)alloc((size_t)128 * 128 * 2);
  ushort* wp3h = (ushort*)alloc((size_t)128 * 64 * 2);
  ushort* wp3l = (ushort*)alloc((size_t)128 * 64 * 2);

  hipMemsetAsync(cnt, 0, (size_t)N_NODES * 4, stream);

  const int EB = (E_EDGES + 255) / 256;  // 6250
  const int GB = (N_NODES + 63) / 64;    // 1563
  const int AB = (N_NODES + 3) / 4;      // 25000

  packw_all_kernel<<<20, 256, 0, stream>>>(W1, wp1h, wp1l, W2, wp2h, wp2l, W3,
                                           wp3h, wp3l);
  rank_kernel<<<EB, 256, 0, stream>>>(dst, cnt, eRank);
  gemm_kernel<128, false><<<GB, 256, 0, stream>>>(x, wp1h, wp1l, h);
  scan_part_kernel<<<SCAN_B, 256, 0, stream>>>(cnt, bsum);
  scan_tops_kernel<<<1, 128, 0, stream>>>(bsum, boff, rowptr);
  scan_write_kernel<<<SCAN_B, 256, 0, stream>>>(cnt, boff, rowptr, dinv);
  place_kernel<<<EB, 256, 0, stream>>>(src, dst, eRank, rowptr, dinv, eSW);

  agg_kernel<128, true><<<AB, 256, 0, stream>>>(h, rowptr, eSW, dinv, b1, A);
  gemm_kernel<128, true><<<GB, 256, 0, stream>>>(A, wp2h, wp2l, h);
  agg_kernel<128, true><<<AB, 256, 0, stream>>>(h, rowptr, eSW, dinv, b2, A);
  gemm_kernel<64, true><<<GB, 256, 0, stream>>>(A, wp3h, wp3l, h);
  agg_kernel<64, false><<<AB, 256, 0, stream>>>(h, rowptr, eSW, dinv, b3,
                                                d_out);
}